// Round 3
// baseline (720.919 us; speedup 1.0000x reference)
//
#include <hip/hip_runtime.h>

static constexpr int NN  = 10000;    // nodes
static constexpr int NE  = 640000;   // edges
static constexpr int INC = 128;
static constexpr int HIDC = 256;
static constexpr int OUTC = 128;
static constexpr int CAP = 128;      // ELL row capacity (max in-degree ~104 for this graph)

static constexpr int FB  = 64;                   // ownership blocks
static constexpr int OWN = (NN + FB - 1) / FB;   // 157 nodes owned per block

// ---- workspace layout (bytes) ----
static constexpr size_t OFF_V    = 0;          // float[256] (zeroed each call)
static constexpr size_t ZBYTES   = 1024;
static constexpr size_t OFF_CNT  = 1024;       // int[10240]   (ownership-written)
static constexpr size_t OFF_CSUM = 41984;      // float[10240] (ownership-written)
static constexpr size_t OFF_DINV = 82944;      // float[10240] (ownership-written)
static constexpr size_t OFF_ELL  = 123904;     // ushort[10000*128] = 2,560,000 B
static constexpr size_t OFF_XA   = 2683904;    // float[10000*128] (16B aligned)

// Ownership fill: block b owns dst in [b*OWN, b*OWN+OWN). Scans full edge list,
// counts + fills ELL with LDS atomics only, then writes cnt/dinv for its rows.
// No global atomics, contiguous ELL writes.
__global__ __launch_bounds__(1024) void k_fill(const int* __restrict__ ei,
                                               int* __restrict__ cnt,
                                               float* __restrict__ dinv,
                                               unsigned short* __restrict__ ell) {
    __shared__ int lcnt[OWN];
    int t = threadIdx.x;
    int base = blockIdx.x * OWN;
    int hi = min(base + OWN, NN);
    for (int i = t; i < OWN; i += 1024) lcnt[i] = 0;
    __syncthreads();
    for (int e = t; e < NE; e += 1024) {
        int d = ei[NE + e];
        int s = ei[e];
        if (d >= base && d < hi) {
            int pos = atomicAdd(&lcnt[d - base], 1);
            if (pos < CAP) ell[d * CAP + pos] = (unsigned short)s;
        }
    }
    __syncthreads();
    for (int i = t; base + i < hi; i += 1024) {
        int c = lcnt[i];
        cnt[base + i] = c;
        dinv[base + i] = rsqrtf((float)(1 + c));   // +1 self loop
    }
}

// Ownership csum: block b owns src in [b*OWN, ...). csum[s] = sum over out-edges
// (s->d) of dinv[d]. dinv staged in LDS; LDS float accumulate; no global atomics.
__global__ __launch_bounds__(1024) void k_csum(const int* __restrict__ ei,
                                               const float* __restrict__ dinv,
                                               float* __restrict__ csum) {
    __shared__ float sdinv[NN];
    __shared__ float lsum[OWN];
    int t = threadIdx.x;
    int base = blockIdx.x * OWN;
    int hi = min(base + OWN, NN);
    for (int i = t; i < NN; i += 1024) sdinv[i] = dinv[i];
    for (int i = t; i < OWN; i += 1024) lsum[i] = 0.f;
    __syncthreads();
    for (int e = t; e < NE; e += 1024) {
        int s = ei[e];
        int d = ei[NE + e];
        if (s >= base && s < hi) {
            atomicAdd(&lsum[s - base], sdinv[d]);
        }
    }
    __syncthreads();
    for (int i = t; base + i < hi; i += 1024) csum[base + i] = lsum[i];
}

// Pure-gather aggregation, 4x unrolled: per iteration the wave has 8 neighbor
// rows (4 per half-wave) in flight. Branchless tail via act-select (su=n when
// inactive keeps every load in-bounds).
// Xa[n] = dinv[n]*(dinv[n]*X[n] + sum_s dinv[s]*X[s])
__global__ __launch_bounds__(256) void k_aggc(const float* __restrict__ x,
                                              const float* __restrict__ dinv,
                                              const int* __restrict__ cnt,
                                              const unsigned short* __restrict__ ell,
                                              float* __restrict__ xa) {
    int lane = threadIdx.x & 63;
    int n = blockIdx.x * 4 + (threadIdx.x >> 6);
    int g = lane & 31;        // float4 chunk within the 128-ch row
    int j = lane >> 5;        // which neighbor of the pair this half-wave takes
    float dn = dinv[n];
    const float4* x4 = (const float4*)x;
    float4 acc = make_float4(0.f, 0.f, 0.f, 0.f);
    if (j == 0) {             // self loop (outer dn applied at the end)
        float4 xs = x4[n * 32 + g];
        acc.x = dn * xs.x; acc.y = dn * xs.y; acc.z = dn * xs.z; acc.w = dn * xs.w;
    }
    int c = cnt[n];
    int base = n * CAP;
    for (int i = 0; i < c; i += 8) {
        int   su[4];
        float ws[4];
        float4 xv[4];
#pragma unroll
        for (int u = 0; u < 4; u++) {
            int idx = i + 2 * u + j;
            bool act = idx < c;
            int raw = (int)ell[base + min(idx, CAP - 1)];
            su[u] = act ? raw : n;
            ws[u] = act ? 1.f : 0.f;
        }
#pragma unroll
        for (int u = 0; u < 4; u++) ws[u] *= dinv[su[u]];
#pragma unroll
        for (int u = 0; u < 4; u++) xv[u] = x4[su[u] * 32 + g];
#pragma unroll
        for (int u = 0; u < 4; u++) {
            acc.x = fmaf(ws[u], xv[u].x, acc.x);
            acc.y = fmaf(ws[u], xv[u].y, acc.y);
            acc.z = fmaf(ws[u], xv[u].z, acc.z);
            acc.w = fmaf(ws[u], xv[u].w, acc.w);
        }
    }
    // combine the two half-wave accumulators
    acc.x += __shfl_down(acc.x, 32);
    acc.y += __shfl_down(acc.y, 32);
    acc.z += __shfl_down(acc.z, 32);
    acc.w += __shfl_down(acc.w, 32);
    if (j == 0) {
        float4 r;
        r.x = dn * acc.x; r.y = dn * acc.y; r.z = dn * acc.z; r.w = dn * acc.w;
        ((float4*)xa)[n * 32 + g] = r;
    }
}

// v[t] = sum_n c[n] * relu( Xa[n,:] . W1[:,t] + b1[t] ),  c[n]=dinv[n]*(dinv[n]+csum[n])
__global__ __launch_bounds__(256) void k_gemmv(const float* __restrict__ xa,
                                               const float* __restrict__ W1,
                                               const float* __restrict__ b1,
                                               const float* __restrict__ dinv,
                                               const float* __restrict__ csum,
                                               float* __restrict__ v) {
    int t = threadIdx.x;
    float w[INC];
#pragma unroll
    for (int k = 0; k < INC; k++) w[k] = W1[k * HIDC + t];
    float bt = b1[t];
    float vt = 0.f;
    for (int n = blockIdx.x; n < NN; n += gridDim.x) {
        const float4* xa4 = (const float4*)(xa + (size_t)n * INC);
        float h = bt;
#pragma unroll
        for (int q = 0; q < INC / 4; q++) {
            float4 xv = xa4[q];
            h = fmaf(xv.x, w[4 * q + 0], h);
            h = fmaf(xv.y, w[4 * q + 1], h);
            h = fmaf(xv.z, w[4 * q + 2], h);
            h = fmaf(xv.w, w[4 * q + 3], h);
        }
        float dn = dinv[n];
        float cn = dn * (dn + csum[n]);
        vt += cn * fmaxf(h, 0.f);
    }
    atomicAdd(&v[t], vt);
}

// out = (1/N) * sum_t v[t]*u[t] + b2.fc_w + fc_b,   u[t] = W2[t,:] . fc_w
__global__ __launch_bounds__(256) void k_final(const float* __restrict__ v,
                                               const float* __restrict__ W2,
                                               const float* __restrict__ b2,
                                               const float* __restrict__ fcw,
                                               const float* __restrict__ fcb,
                                               float* __restrict__ out) {
    __shared__ float red[256];
    int t = threadIdx.x;
    float u = 0.f;
#pragma unroll 4
    for (int j = 0; j < OUTC; j++) u = fmaf(W2[t * OUTC + j], fcw[j], u);
    float contrib = v[t] * u * (1.0f / (float)NN);
    if (t < OUTC) contrib += b2[t] * fcw[t];
    red[t] = contrib;
    __syncthreads();
    for (int s = 128; s > 0; s >>= 1) {
        if (t < s) red[t] += red[t + s];
        __syncthreads();
    }
    if (t == 0) out[0] = red[0] + fcb[0];
}

extern "C" void kernel_launch(void* const* d_in, const int* in_sizes, int n_in,
                              void* d_out, int out_size, void* d_ws, size_t ws_size,
                              hipStream_t stream) {
    const float* x   = (const float*)d_in[0];
    const int*   ei  = (const int*)d_in[1];
    const float* W1  = (const float*)d_in[2];
    const float* b1  = (const float*)d_in[3];
    const float* W2  = (const float*)d_in[4];
    const float* b2  = (const float*)d_in[5];
    const float* fcw = (const float*)d_in[6];
    const float* fcb = (const float*)d_in[7];
    float* out = (float*)d_out;

    char* ws = (char*)d_ws;
    float*          v    = (float*)(ws + OFF_V);
    int*            cnt  = (int*)(ws + OFF_CNT);
    float*          csum = (float*)(ws + OFF_CSUM);
    float*          dinv = (float*)(ws + OFF_DINV);
    unsigned short* ell  = (unsigned short*)(ws + OFF_ELL);
    float*          xa   = (float*)(ws + OFF_XA);

    hipMemsetAsync(v, 0, ZBYTES, stream);

    k_fill<<<FB, 1024, 0, stream>>>(ei, cnt, dinv, ell);
    k_csum<<<FB, 1024, 0, stream>>>(ei, dinv, csum);
    k_aggc<<<NN / 4, 256, 0, stream>>>(x, dinv, cnt, ell, xa);
    k_gemmv<<<512, 256, 0, stream>>>(xa, W1, b1, dinv, csum, v);
    k_final<<<1, 256, 0, stream>>>(v, W2, b2, fcw, fcb, out);
}

// Round 4
// 216.547 us; speedup vs baseline: 3.3292x; 3.3292x over previous
//
#include <hip/hip_runtime.h>
#include <hip/hip_fp16.h>

static constexpr int NN  = 10000;    // nodes
static constexpr int NE  = 640000;   // edges
static constexpr int INC = 128;
static constexpr int HIDC = 256;
static constexpr int OUTC = 128;
static constexpr int CAP = 128;      // ELL row capacity (max in-degree ~ 64 + 4.3*8 ≈ 98)

// ---- workspace layout (bytes) ----  (keep total <= ~7.8 MB, proven available)
static constexpr size_t OFF_CNT  = 0;          // int[10240]   (atomically counted)
static constexpr size_t OFF_CSUM = 40960;      // float[10240] (atomically accumulated)
static constexpr size_t OFF_V    = 81920;      // float[256]
static constexpr size_t ZBYTES   = 82944;      // cnt+csum+v zeroed each call
static constexpr size_t OFF_DINV = 82944;      // float[10240]
static constexpr size_t OFF_ELL  = 123904;     // ushort[10000*128] = 2,560,000
static constexpr size_t OFF_XH   = 2683904;    // half[10000*128]  = 2,560,000 (L2-resident!)
static constexpr size_t OFF_XA   = 5243904;    // half[10000*128]  = 2,560,000  -> end 7,803,904

// X fp32 -> fp16 (2.56 MB: fits in every XCD's 4 MiB L2 for the gather phase)
__global__ __launch_bounds__(256) void k_half(const float* __restrict__ x,
                                              __half* __restrict__ xh) {
    int i = (blockIdx.x * 256 + threadIdx.x) * 4;
    if (i >= NN * INC) return;
    float4 v = *(const float4*)(x + i);
    __half2 a = __floats2half2_rn(v.x, v.y);
    __half2 b = __floats2half2_rn(v.z, v.w);
    __half2 o[2] = {a, b};
    *(float2*)(xh + i) = *(float2*)o;
}

// Edge-parallel count+fill (R2 pattern — the one that worked).
__global__ __launch_bounds__(256) void k_fill(const int* __restrict__ ei,
                                              int* __restrict__ cnt,
                                              unsigned short* __restrict__ ell) {
    int e = blockIdx.x * 256 + threadIdx.x;
    if (e >= NE) return;
    int s = ei[e];
    int d = ei[NE + e];
    int pos = atomicAdd(&cnt[d], 1);
    if (pos < CAP) ell[d * CAP + pos] = (unsigned short)s;
}

__global__ __launch_bounds__(256) void k_dinv(const int* __restrict__ cnt,
                                              float* __restrict__ dinv) {
    int n = blockIdx.x * 256 + threadIdx.x;
    if (n < NN) dinv[n] = rsqrtf((float)(1 + cnt[n]));  // +1 self loop
}

// Wave-per-node aggregation over fp16 X, fused csum atomics.
// Lane = g + 16*j: g in [0,16) = 16B chunk (8 channels), j in [0,4) = neighbor group.
// 2x unroll -> 8 neighbor rows in flight per wave.
// Xa[n] = fp16( dinv[n]*(dinv[n]*X[n] + sum_s dinv[s]*Xh[s]) );  csum[s] += dinv[n].
__global__ __launch_bounds__(256) void k_aggc(const float* __restrict__ x,
                                              const __half* __restrict__ xh,
                                              const float* __restrict__ dinv,
                                              const int* __restrict__ cnt,
                                              const unsigned short* __restrict__ ell,
                                              float* __restrict__ csum,
                                              __half* __restrict__ xa) {
    int lane = threadIdx.x & 63;
    int n = blockIdx.x * 4 + (threadIdx.x >> 6);
    int g = lane & 15;        // 16B chunk within the 256B fp16 row
    int j = lane >> 4;        // neighbor group
    float dn = dinv[n];
    float acc[8];
#pragma unroll
    for (int k = 0; k < 8; k++) acc[k] = 0.f;
    if (j == 0) {             // self loop from fp32 X (full precision), outer dn at end
        const float4* x4 = (const float4*)x;
        float4 a = x4[n * 32 + 2 * g];
        float4 b = x4[n * 32 + 2 * g + 1];
        acc[0] = dn * a.x; acc[1] = dn * a.y; acc[2] = dn * a.z; acc[3] = dn * a.w;
        acc[4] = dn * b.x; acc[5] = dn * b.y; acc[6] = dn * b.z; acc[7] = dn * b.w;
    }
    int c = cnt[n];
    int base = n * CAP;
    for (int i = 0; i < c; i += 8) {
        int   su[2];
        float ws[2];
        float4 xv[2];
#pragma unroll
        for (int u = 0; u < 2; u++) {
            int idx = i + 4 * u + j;
            bool act = idx < c;
            int raw = (int)ell[base + min(idx, CAP - 1)];
            su[u] = raw;
            ws[u] = act ? 1.f : 0.f;
            if (act && g == 0) atomicAdd(&csum[raw], dn);   // fire-and-forget
        }
#pragma unroll
        for (int u = 0; u < 2; u++) ws[u] *= dinv[su[u]];
#pragma unroll
        for (int u = 0; u < 2; u++)
            xv[u] = *(const float4*)(xh + su[u] * INC + 8 * g);
#pragma unroll
        for (int u = 0; u < 2; u++) {
            const __half2* h2 = (const __half2*)&xv[u];
#pragma unroll
            for (int q = 0; q < 4; q++) {
                float2 f = __half22float2(h2[q]);
                acc[2 * q]     = fmaf(ws[u], f.x, acc[2 * q]);
                acc[2 * q + 1] = fmaf(ws[u], f.y, acc[2 * q + 1]);
            }
        }
    }
    // combine the 4 neighbor-group accumulators
#pragma unroll
    for (int k = 0; k < 8; k++) {
        acc[k] += __shfl_down(acc[k], 32);
        acc[k] += __shfl_down(acc[k], 16);
    }
    if (j == 0) {
        __half2 o[4];
#pragma unroll
        for (int q = 0; q < 4; q++)
            o[q] = __floats2half2_rn(dn * acc[2 * q], dn * acc[2 * q + 1]);
        *(float4*)(xa + n * INC + 8 * g) = *(float4*)o;
    }
}

// v[t] = sum_n c[n] * relu( Xa[n,:] . W1[:,t] + b1[t] ),  c[n]=dinv[n]*(dinv[n]+csum[n])
__global__ __launch_bounds__(256) void k_gemmv(const __half* __restrict__ xa,
                                               const float* __restrict__ W1,
                                               const float* __restrict__ b1,
                                               const float* __restrict__ dinv,
                                               const float* __restrict__ csum,
                                               float* __restrict__ v) {
    int t = threadIdx.x;
    float w[INC];
#pragma unroll
    for (int k = 0; k < INC; k++) w[k] = W1[k * HIDC + t];
    float bt = b1[t];
    float vt = 0.f;
    for (int n = blockIdx.x; n < NN; n += gridDim.x) {
        const float4* r4 = (const float4*)(xa + (size_t)n * INC);
        float h = bt;
#pragma unroll
        for (int q = 0; q < INC / 8; q++) {
            float4 xv = r4[q];
            const __half2* h2 = (const __half2*)&xv;
#pragma unroll
            for (int p = 0; p < 4; p++) {
                float2 f = __half22float2(h2[p]);
                h = fmaf(f.x, w[8 * q + 2 * p], h);
                h = fmaf(f.y, w[8 * q + 2 * p + 1], h);
            }
        }
        float dn = dinv[n];
        float cn = dn * (dn + csum[n]);
        vt += cn * fmaxf(h, 0.f);
    }
    atomicAdd(&v[t], vt);
}

// out = (1/N) * sum_t v[t]*u[t] + b2.fc_w + fc_b,   u[t] = W2[t,:] . fc_w
__global__ __launch_bounds__(256) void k_final(const float* __restrict__ v,
                                               const float* __restrict__ W2,
                                               const float* __restrict__ b2,
                                               const float* __restrict__ fcw,
                                               const float* __restrict__ fcb,
                                               float* __restrict__ out) {
    __shared__ float red[256];
    int t = threadIdx.x;
    float u = 0.f;
#pragma unroll 4
    for (int j = 0; j < OUTC; j++) u = fmaf(W2[t * OUTC + j], fcw[j], u);
    float contrib = v[t] * u * (1.0f / (float)NN);
    if (t < OUTC) contrib += b2[t] * fcw[t];
    red[t] = contrib;
    __syncthreads();
    for (int s = 128; s > 0; s >>= 1) {
        if (t < s) red[t] += red[t + s];
        __syncthreads();
    }
    if (t == 0) out[0] = red[0] + fcb[0];
}

extern "C" void kernel_launch(void* const* d_in, const int* in_sizes, int n_in,
                              void* d_out, int out_size, void* d_ws, size_t ws_size,
                              hipStream_t stream) {
    const float* x   = (const float*)d_in[0];
    const int*   ei  = (const int*)d_in[1];
    const float* W1  = (const float*)d_in[2];
    const float* b1  = (const float*)d_in[3];
    const float* W2  = (const float*)d_in[4];
    const float* b2  = (const float*)d_in[5];
    const float* fcw = (const float*)d_in[6];
    const float* fcb = (const float*)d_in[7];
    float* out = (float*)d_out;

    char* ws = (char*)d_ws;
    int*            cnt  = (int*)(ws + OFF_CNT);
    float*          csum = (float*)(ws + OFF_CSUM);
    float*          v    = (float*)(ws + OFF_V);
    float*          dinv = (float*)(ws + OFF_DINV);
    unsigned short* ell  = (unsigned short*)(ws + OFF_ELL);
    __half*         xh   = (__half*)(ws + OFF_XH);
    __half*         xa   = (__half*)(ws + OFF_XA);

    hipMemsetAsync(ws, 0, ZBYTES, stream);

    k_half<<<(NN * INC / 4 + 255) / 256, 256, 0, stream>>>(x, xh);
    k_fill<<<(NE + 255) / 256, 256, 0, stream>>>(ei, cnt, ell);
    k_dinv<<<(NN + 255) / 256, 256, 0, stream>>>(cnt, dinv);
    k_aggc<<<NN / 4, 256, 0, stream>>>(x, xh, dinv, cnt, ell, csum, xa);
    k_gemmv<<<512, 256, 0, stream>>>(xa, W1, b1, dinv, csum, v);
    k_final<<<1, 256, 0, stream>>>(v, W2, b2, fcw, fcb, out);
}

// Round 5
// 185.537 us; speedup vs baseline: 3.8856x; 1.1671x over previous
//
#include <hip/hip_runtime.h>
#include <hip/hip_fp16.h>

static constexpr int NN  = 10000;    // nodes
static constexpr int NE  = 640000;   // edges
static constexpr int INC = 128;
static constexpr int HIDC = 256;
static constexpr int OUTC = 128;
static constexpr int CAP = 128;      // ELL row capacity (max in-degree ~104 for this graph)

static constexpr int FB  = 64;       // fill slice blocks  (NE/FB = 10000 edges each)
static constexpr int CB  = 32;       // csum slice blocks  (NE/CB = 20000 edges each)
static constexpr int NP  = 10240;    // padded node stride

// ---- workspace layout (bytes), total 7,803,904 (same proven footprint as R4) ----
static constexpr size_t OFF_V    = 0;          // float[256] (zeroed each call)
static constexpr size_t ZBYTES   = 1024;
static constexpr size_t OFF_CNT  = 1024;       // int[10240]
static constexpr size_t OFF_DINV = 41984;      // float[10240]
static constexpr size_t OFF_CSUM = 82944;      // float[10240]
static constexpr size_t OFF_ELL  = 123904;     // ushort[10000*128] = 2,560,000
static constexpr size_t OFF_XH   = 2683904;    // half[10000*128]   = 2,560,000
static constexpr size_t OFF_XA   = 5243904;    // 2,560,000 region, TIME-SHARED:
                                               //   phase A: countpart/offsets ushort[64][10240] (1.31 MB)
                                               //   phase B: csumpart float[32][10240] (1.31 MB)
                                               //   phase C: xa half[10000*128]

// X fp32 -> fp16 (2.56 MB: L2-resident for the gather phase)
__global__ __launch_bounds__(256) void k_half(const float* __restrict__ x,
                                              __half* __restrict__ xh) {
    int i = (blockIdx.x * 256 + threadIdx.x) * 4;
    if (i >= NN * INC) return;
    float4 v = *(const float4*)(x + i);
    __half2 a = __floats2half2_rn(v.x, v.y);
    __half2 b = __floats2half2_rn(v.z, v.w);
    __half2 o[2] = {a, b};
    *(float2*)(xh + i) = *(float2*)o;
}

// Slice-parallel degree count: block b histograms its own 10000-edge slice in
// LDS, writes per-block partial counts. Zero global atomics, zero read-amp.
__global__ __launch_bounds__(1024) void k_count(const int* __restrict__ ei,
                                                unsigned short* __restrict__ cpart) {
    __shared__ int lh[NN];
    int t = threadIdx.x, b = blockIdx.x;
    for (int i = t; i < NN; i += 1024) lh[i] = 0;
    __syncthreads();
    int e0 = b * (NE / FB);
    for (int k = t; k < NE / FB; k += 1024) {
        int d = ei[NE + e0 + k];
        atomicAdd(&lh[d], 1);
    }
    __syncthreads();
    for (int i = t; i < NN; i += 1024) cpart[b * NP + i] = (unsigned short)lh[i];
}

// Per node: scan the 64 partial counts -> in-place exclusive per-block offsets,
// total cnt, dinv.
__global__ __launch_bounds__(256) void k_scan(unsigned short* __restrict__ cpart,
                                              int* __restrict__ cnt,
                                              float* __restrict__ dinv) {
    int n = blockIdx.x * 256 + threadIdx.x;
    if (n >= NN) return;
    int run = 0;
#pragma unroll 8
    for (int b = 0; b < FB; b++) {
        int c = cpart[b * NP + n];
        cpart[b * NP + n] = (unsigned short)run;
        run += c;
    }
    cnt[n] = run;
    dinv[n] = rsqrtf((float)(1 + run));   // +1 self loop
}

// Slice-parallel ELL fill: LDS-only atomics; global position = block offset +
// local LDS counter.
__global__ __launch_bounds__(1024) void k_fill2(const int* __restrict__ ei,
                                                const unsigned short* __restrict__ cpart,
                                                unsigned short* __restrict__ ell) {
    __shared__ int lh[NN];
    __shared__ unsigned short soff[NN];
    int t = threadIdx.x, b = blockIdx.x;
    for (int i = t; i < NN; i += 1024) {
        lh[i] = 0;
        soff[i] = cpart[b * NP + i];
    }
    __syncthreads();
    int e0 = b * (NE / FB);
    for (int k = t; k < NE / FB; k += 1024) {
        int s = ei[e0 + k];
        int d = ei[NE + e0 + k];
        int pos = (int)soff[d] + atomicAdd(&lh[d], 1);
        if (pos < CAP) ell[d * CAP + pos] = (unsigned short)s;
    }
}

// Slice-parallel csum: csum[s] = sum over out-edges (s->d) of dinv[d].
// LDS float histogram per slice, partials reduced by k_csumred.
__global__ __launch_bounds__(1024) void k_csum(const int* __restrict__ ei,
                                               const float* __restrict__ dinv,
                                               float* __restrict__ cspart) {
    __shared__ float lc[NN];
    int t = threadIdx.x, b = blockIdx.x;
    for (int i = t; i < NN; i += 1024) lc[i] = 0.f;
    __syncthreads();
    int e0 = b * (NE / CB);
    for (int k = t; k < NE / CB; k += 1024) {
        int s = ei[e0 + k];
        int d = ei[NE + e0 + k];
        atomicAdd(&lc[s], dinv[d]);
    }
    __syncthreads();
    for (int i = t; i < NN; i += 1024) cspart[b * NP + i] = lc[i];
}

__global__ __launch_bounds__(256) void k_csumred(const float* __restrict__ cspart,
                                                 float* __restrict__ csum) {
    int n = blockIdx.x * 256 + threadIdx.x;
    if (n >= NN) return;
    float s = 0.f;
#pragma unroll
    for (int b = 0; b < CB; b++) s += cspart[b * NP + n];
    csum[n] = s;
}

// Pure-gather aggregation over fp16 X. Wave = node; lane = g + 16*j
// (g: 16B chunk of the 256B row, j: neighbor group). 4x unroll -> 16 rows in
// flight per wave. NO atomics.
// Xa[n] = fp16( dinv[n]*(dinv[n]*X[n] + sum_s dinv[s]*Xh[s]) )
__global__ __launch_bounds__(256) void k_aggc(const float* __restrict__ x,
                                              const __half* __restrict__ xh,
                                              const float* __restrict__ dinv,
                                              const int* __restrict__ cnt,
                                              const unsigned short* __restrict__ ell,
                                              __half* __restrict__ xa) {
    int lane = threadIdx.x & 63;
    int n = blockIdx.x * 4 + (threadIdx.x >> 6);
    int g = lane & 15;
    int j = lane >> 4;
    float dn = dinv[n];
    float acc[8];
#pragma unroll
    for (int k = 0; k < 8; k++) acc[k] = 0.f;
    if (j == 0) {             // self loop from fp32 X (outer dn applied at end)
        const float4* x4 = (const float4*)x;
        float4 a = x4[n * 32 + 2 * g];
        float4 b = x4[n * 32 + 2 * g + 1];
        acc[0] = dn * a.x; acc[1] = dn * a.y; acc[2] = dn * a.z; acc[3] = dn * a.w;
        acc[4] = dn * b.x; acc[5] = dn * b.y; acc[6] = dn * b.z; acc[7] = dn * b.w;
    }
    int c = cnt[n];
    int base = n * CAP;
    for (int i = 0; i < c; i += 16) {
        int   su[4];
        float ws[4];
        float4 xv[4];
#pragma unroll
        for (int u = 0; u < 4; u++) {
            int idx = i + 4 * u + j;
            bool act = idx < c;
            int raw = (int)ell[base + min(idx, CAP - 1)];
            su[u] = act ? raw : n;         // in-bounds dummy row when inactive
            ws[u] = act ? 1.f : 0.f;
        }
#pragma unroll
        for (int u = 0; u < 4; u++) ws[u] *= dinv[su[u]];
#pragma unroll
        for (int u = 0; u < 4; u++)
            xv[u] = *(const float4*)(xh + su[u] * INC + 8 * g);
#pragma unroll
        for (int u = 0; u < 4; u++) {
            const __half2* h2 = (const __half2*)&xv[u];
#pragma unroll
            for (int q = 0; q < 4; q++) {
                float2 f = __half22float2(h2[q]);
                acc[2 * q]     = fmaf(ws[u], f.x, acc[2 * q]);
                acc[2 * q + 1] = fmaf(ws[u], f.y, acc[2 * q + 1]);
            }
        }
    }
#pragma unroll
    for (int k = 0; k < 8; k++) {
        acc[k] += __shfl_down(acc[k], 32);
        acc[k] += __shfl_down(acc[k], 16);
    }
    if (j == 0) {
        __half2 o[4];
#pragma unroll
        for (int q = 0; q < 4; q++)
            o[q] = __floats2half2_rn(dn * acc[2 * q], dn * acc[2 * q + 1]);
        *(float4*)(xa + n * INC + 8 * g) = *(float4*)o;
    }
}

// v[t] = sum_n c[n] * relu( Xa[n,:] . W1[:,t] + b1[t] ),  c[n]=dinv[n]*(dinv[n]+csum[n])
__global__ __launch_bounds__(256) void k_gemmv(const __half* __restrict__ xa,
                                               const float* __restrict__ W1,
                                               const float* __restrict__ b1,
                                               const float* __restrict__ dinv,
                                               const float* __restrict__ csum,
                                               float* __restrict__ v) {
    int t = threadIdx.x;
    float w[INC];
#pragma unroll
    for (int k = 0; k < INC; k++) w[k] = W1[k * HIDC + t];
    float bt = b1[t];
    float vt = 0.f;
    for (int n = blockIdx.x; n < NN; n += gridDim.x) {
        const float4* r4 = (const float4*)(xa + (size_t)n * INC);
        float h = bt;
#pragma unroll
        for (int q = 0; q < INC / 8; q++) {
            float4 xv = r4[q];
            const __half2* h2 = (const __half2*)&xv;
#pragma unroll
            for (int p = 0; p < 4; p++) {
                float2 f = __half22float2(h2[p]);
                h = fmaf(f.x, w[8 * q + 2 * p], h);
                h = fmaf(f.y, w[8 * q + 2 * p + 1], h);
            }
        }
        float dn = dinv[n];
        float cn = dn * (dn + csum[n]);
        vt += cn * fmaxf(h, 0.f);
    }
    atomicAdd(&v[t], vt);
}

// out = (1/N) * sum_t v[t]*u[t] + b2.fc_w + fc_b,   u[t] = W2[t,:] . fc_w
__global__ __launch_bounds__(256) void k_final(const float* __restrict__ v,
                                               const float* __restrict__ W2,
                                               const float* __restrict__ b2,
                                               const float* __restrict__ fcw,
                                               const float* __restrict__ fcb,
                                               float* __restrict__ out) {
    __shared__ float red[256];
    int t = threadIdx.x;
    float u = 0.f;
#pragma unroll 4
    for (int j = 0; j < OUTC; j++) u = fmaf(W2[t * OUTC + j], fcw[j], u);
    float contrib = v[t] * u * (1.0f / (float)NN);
    if (t < OUTC) contrib += b2[t] * fcw[t];
    red[t] = contrib;
    __syncthreads();
    for (int s = 128; s > 0; s >>= 1) {
        if (t < s) red[t] += red[t + s];
        __syncthreads();
    }
    if (t == 0) out[0] = red[0] + fcb[0];
}

extern "C" void kernel_launch(void* const* d_in, const int* in_sizes, int n_in,
                              void* d_out, int out_size, void* d_ws, size_t ws_size,
                              hipStream_t stream) {
    const float* x   = (const float*)d_in[0];
    const int*   ei  = (const int*)d_in[1];
    const float* W1  = (const float*)d_in[2];
    const float* b1  = (const float*)d_in[3];
    const float* W2  = (const float*)d_in[4];
    const float* b2  = (const float*)d_in[5];
    const float* fcw = (const float*)d_in[6];
    const float* fcb = (const float*)d_in[7];
    float* out = (float*)d_out;

    char* ws = (char*)d_ws;
    float*          v      = (float*)(ws + OFF_V);
    int*            cnt    = (int*)(ws + OFF_CNT);
    float*          dinv   = (float*)(ws + OFF_DINV);
    float*          csum   = (float*)(ws + OFF_CSUM);
    unsigned short* ell    = (unsigned short*)(ws + OFF_ELL);
    __half*         xh     = (__half*)(ws + OFF_XH);
    unsigned short* cpart  = (unsigned short*)(ws + OFF_XA);  // phase A
    float*          cspart = (float*)(ws + OFF_XA);           // phase B
    __half*         xa     = (__half*)(ws + OFF_XA);          // phase C

    hipMemsetAsync(ws, 0, ZBYTES, stream);

    k_half<<<(NN * INC / 4 + 255) / 256, 256, 0, stream>>>(x, xh);
    k_count<<<FB, 1024, 0, stream>>>(ei, cpart);
    k_scan<<<(NN + 255) / 256, 256, 0, stream>>>(cpart, cnt, dinv);
    k_fill2<<<FB, 1024, 0, stream>>>(ei, cpart, ell);
    k_csum<<<CB, 1024, 0, stream>>>(ei, dinv, cspart);
    k_csumred<<<(NN + 255) / 256, 256, 0, stream>>>(cspart, csum);
    k_aggc<<<NN / 4, 256, 0, stream>>>(x, xh, dinv, cnt, ell, xa);
    k_gemmv<<<512, 256, 0, stream>>>(xa, W1, b1, dinv, csum, v);
    k_final<<<1, 256, 0, stream>>>(v, W2, b2, fcw, fcb, out);
}

// Round 6
// 185.132 us; speedup vs baseline: 3.8941x; 1.0022x over previous
//
#include <hip/hip_runtime.h>
#include <hip/hip_fp16.h>

static constexpr int NN  = 10000;    // nodes
static constexpr int NE  = 640000;   // edges
static constexpr int INC = 128;
static constexpr int HIDC = 256;
static constexpr int OUTC = 128;
static constexpr int CAP = 128;      // ELL row capacity (max in-degree ~104)

static constexpr int FB = 128;       // fill/count slice blocks (5000 edges each)
static constexpr int CB = 64;        // csum slice blocks (10000 edges each)
static constexpr int HB = 313;       // half-scale blocks (1024 thr * 4 floats)
static constexpr int AB = 2500;      // agg blocks (4 nodes each)
static constexpr int NP = 10240;     // padded node stride

// ---- workspace layout (bytes); ws_size is ~256 MB (harness poison evidence) ----
static constexpr size_t OFF_V     = 0;          // float[256]
static constexpr size_t OFF_DONE  = 1024;       // uint[1]
static constexpr size_t ZBYTES    = 2048;       // zeroed each call
static constexpr size_t OFF_CNT   = 2048;       // int[10240]
static constexpr size_t OFF_DINV  = 43008;      // float[10240]
static constexpr size_t OFF_CSUM  = 83968;      // float[10240]
static constexpr size_t OFF_ELL   = 124928;     // ushort[10000*128] = 2,560,000
static constexpr size_t OFF_XH    = 2684928;    // half[10000*128]   = 2,560,000
static constexpr size_t OFF_XA    = 5244928;    // half[10000*128]   = 2,560,000
static constexpr size_t OFF_CPART = 7804928;    // ushort[128*10240] = 2,621,440
static constexpr size_t OFF_CSP   = 10426368;   // float[64*10240]   = 2,621,440

// ---- K1: slice-parallel degree count (LDS histogram, no global atomics) ----
__global__ __launch_bounds__(1024) void k_count(const int* __restrict__ ei,
                                                unsigned short* __restrict__ cpart) {
    __shared__ int lh[NN];
    int t = threadIdx.x, b = blockIdx.x;
    for (int i = t; i < NN; i += 1024) lh[i] = 0;
    __syncthreads();
    int e0 = b * (NE / FB);
    for (int k = t; k < NE / FB; k += 1024) atomicAdd(&lh[ei[NE + e0 + k]], 1);
    __syncthreads();
    for (int i = t; i < NN; i += 1024) cpart[b * NP + i] = (unsigned short)lh[i];
}

// ---- K2: per-node scan of partials -> per-block offsets, cnt, dinv ----
__global__ __launch_bounds__(1024) void k_scan(unsigned short* __restrict__ cpart,
                                               int* __restrict__ cnt,
                                               float* __restrict__ dinv) {
    int n = blockIdx.x * 1024 + threadIdx.x;
    if (n >= NN) return;
    int run = 0;
#pragma unroll 8
    for (int b = 0; b < FB; b++) {
        int c = cpart[b * NP + n];
        cpart[b * NP + n] = (unsigned short)run;
        run += c;
    }
    cnt[n] = run;
    dinv[n] = rsqrtf((float)(1 + run));   // +1 self loop
}

// ---- K3 (fused): ELL fill | csum partials | dinv-scaled fp16 X ----
// blocks [0,FB): fill; [FB,FB+CB): csum; [FB+CB, FB+CB+HB): half-scale.
__global__ __launch_bounds__(1024) void k_prep(const int* __restrict__ ei,
                                               const float* __restrict__ x,
                                               const float* __restrict__ dinv,
                                               const unsigned short* __restrict__ cpart,
                                               unsigned short* __restrict__ ell,
                                               float* __restrict__ cspart,
                                               __half* __restrict__ xh) {
    __shared__ int lh[NN];                 // int counters (fill) / float sums (csum)
    __shared__ unsigned short soff[NN];
    int t = threadIdx.x, b = blockIdx.x;
    if (b < FB) {
        // ELL fill: global slot = scanned block offset + LDS-local counter
        for (int i = t; i < NN; i += 1024) { lh[i] = 0; soff[i] = cpart[b * NP + i]; }
        __syncthreads();
        int e0 = b * (NE / FB);
        for (int k = t; k < NE / FB; k += 1024) {
            int s = ei[e0 + k];
            int d = ei[NE + e0 + k];
            int pos = (int)soff[d] + atomicAdd(&lh[d], 1);
            if (pos < CAP) ell[d * CAP + pos] = (unsigned short)s;
        }
    } else if (b < FB + CB) {
        // csum[s] partials: sum over out-edges (s->d) of dinv[d]
        int bb = b - FB;
        float* lc = (float*)lh;
        for (int i = t; i < NN; i += 1024) lc[i] = 0.f;
        __syncthreads();
        int e0 = bb * (NE / CB);
        for (int k = t; k < NE / CB; k += 1024) {
            int s = ei[e0 + k];
            int d = ei[NE + e0 + k];
            atomicAdd(&lc[s], dinv[d]);
        }
        __syncthreads();
        for (int i = t; i < NN; i += 1024) cspart[bb * NP + i] = lc[i];
    } else {
        // xh[n,:] = fp16( dinv[n] * X[n,:] )  — pre-scaled gather operand
        int gid = (b - FB - CB) * 1024 + t;
        int i = gid * 4;
        if (i < NN * INC) {
            float4 v = *(const float4*)(x + i);
            float dv = dinv[i >> 7];
            __half2 o[2] = {__floats2half2_rn(dv * v.x, dv * v.y),
                            __floats2half2_rn(dv * v.z, dv * v.w)};
            *(float2*)(xh + i) = *(float2*)o;
        }
    }
}

// ---- K4 (fused): aggregation gather | csum reduce ----
// Xa[n] = fp16( dinv[n]*(dinv[n]*X[n] + sum_s xh[s]) ), xh pre-scaled by dinv[s].
// Wave=node; lane = g + 16*j (g: 16B chunk, j: neighbor group); unroll 8 ->
// 32 rows in flight per wave.
__global__ __launch_bounds__(256) void k_agg(const float* __restrict__ x,
                                             const __half* __restrict__ xh,
                                             const float* __restrict__ dinv,
                                             const int* __restrict__ cnt,
                                             const unsigned short* __restrict__ ell,
                                             const float* __restrict__ cspart,
                                             float* __restrict__ csum,
                                             __half* __restrict__ xa) {
    int b = blockIdx.x;
    if (b >= AB) {   // csum partial reduce (40 tail blocks)
        int n = (b - AB) * 256 + threadIdx.x;
        if (n < NN) {
            float s = 0.f;
#pragma unroll
            for (int bb = 0; bb < CB; bb++) s += cspart[bb * NP + n];
            csum[n] = s;
        }
        return;
    }
    int lane = threadIdx.x & 63;
    int n = b * 4 + (threadIdx.x >> 6);
    int g = lane & 15;
    int j = lane >> 4;
    float dn = dinv[n];
    float acc[8];
#pragma unroll
    for (int k = 0; k < 8; k++) acc[k] = 0.f;
    if (j == 0) {             // self loop from fp32 X (outer dn applied at end)
        const float4* x4 = (const float4*)x;
        float4 a = x4[n * 32 + 2 * g];
        float4 c4 = x4[n * 32 + 2 * g + 1];
        acc[0] = dn * a.x;  acc[1] = dn * a.y;  acc[2] = dn * a.z;  acc[3] = dn * a.w;
        acc[4] = dn * c4.x; acc[5] = dn * c4.y; acc[6] = dn * c4.z; acc[7] = dn * c4.w;
    }
    int c = cnt[n];
    int base = n * CAP;
    for (int i = 0; i < c; i += 32) {
        int   su[8];
        float ws[8];
        float4 xv[8];
#pragma unroll
        for (int u = 0; u < 8; u++) {
            int idx = i + 4 * u + j;
            bool act = idx < c;
            int raw = (int)ell[base + min(idx, CAP - 1)];
            su[u] = act ? raw : n;        // in-bounds dummy row when inactive
            ws[u] = act ? 1.f : 0.f;
        }
#pragma unroll
        for (int u = 0; u < 8; u++)
            xv[u] = *(const float4*)(xh + su[u] * INC + 8 * g);
#pragma unroll
        for (int u = 0; u < 8; u++) {
            const __half2* h2 = (const __half2*)&xv[u];
#pragma unroll
            for (int q = 0; q < 4; q++) {
                float2 f = __half22float2(h2[q]);
                acc[2 * q]     = fmaf(ws[u], f.x, acc[2 * q]);
                acc[2 * q + 1] = fmaf(ws[u], f.y, acc[2 * q + 1]);
            }
        }
    }
#pragma unroll
    for (int k = 0; k < 8; k++) {
        acc[k] += __shfl_down(acc[k], 32);
        acc[k] += __shfl_down(acc[k], 16);
    }
    if (j == 0) {
        __half2 o[4];
#pragma unroll
        for (int q = 0; q < 4; q++)
            o[q] = __floats2half2_rn(dn * acc[2 * q], dn * acc[2 * q + 1]);
        *(float4*)(xa + n * INC + 8 * g) = *(float4*)o;
    }
}

// ---- K5 (fused): gemmv + final scalar via last-block arrival counter ----
// v[t] = sum_n c[n]*relu(Xa[n,:].W1[:,t]+b1[t]);  out = mean contraction.
__global__ __launch_bounds__(256) void k_gemmv(const __half* __restrict__ xa,
                                               const float* __restrict__ W1,
                                               const float* __restrict__ b1,
                                               const float* __restrict__ dinv,
                                               const float* __restrict__ csum,
                                               float* __restrict__ v,
                                               unsigned int* __restrict__ done,
                                               const float* __restrict__ W2,
                                               const float* __restrict__ b2,
                                               const float* __restrict__ fcw,
                                               const float* __restrict__ fcb,
                                               float* __restrict__ out) {
    int t = threadIdx.x;
    float w[INC];
#pragma unroll
    for (int k = 0; k < INC; k++) w[k] = W1[k * HIDC + t];
    float bt = b1[t];
    float vt = 0.f;
    for (int n = blockIdx.x; n < NN; n += gridDim.x) {
        const float4* r4 = (const float4*)(xa + (size_t)n * INC);
        float h = bt;
#pragma unroll
        for (int q = 0; q < INC / 8; q++) {
            float4 xv = r4[q];
            const __half2* h2 = (const __half2*)&xv;
#pragma unroll
            for (int p = 0; p < 4; p++) {
                float2 f = __half22float2(h2[p]);
                h = fmaf(f.x, w[8 * q + 2 * p], h);
                h = fmaf(f.y, w[8 * q + 2 * p + 1], h);
            }
        }
        float dn = dinv[n];
        float cn = dn * (dn + csum[n]);
        vt += cn * fmaxf(h, 0.f);
    }
    atomicAdd(&v[t], vt);
    __threadfence();
    __shared__ bool last;
    if (t == 0) {
        unsigned int old = __hip_atomic_fetch_add(done, 1u, __ATOMIC_ACQ_REL,
                                                  __HIP_MEMORY_SCOPE_AGENT);
        last = (old == gridDim.x - 1);
    }
    __syncthreads();
    if (!last) return;
    // final phase: out = (1/N) * sum_t v[t]*u[t] + b2.fc_w + fc_b, u = W2.fc_w
    __shared__ float red[256];
    float u = 0.f;
#pragma unroll 4
    for (int jj = 0; jj < OUTC; jj++) u = fmaf(W2[t * OUTC + jj], fcw[jj], u);
    float vt2 = __hip_atomic_load(&v[t], __ATOMIC_ACQUIRE, __HIP_MEMORY_SCOPE_AGENT);
    float contrib = vt2 * u * (1.0f / (float)NN);
    if (t < OUTC) contrib += b2[t] * fcw[t];
    red[t] = contrib;
    __syncthreads();
    for (int s = 128; s > 0; s >>= 1) {
        if (t < s) red[t] += red[t + s];
        __syncthreads();
    }
    if (t == 0) out[0] = red[0] + fcb[0];
}

extern "C" void kernel_launch(void* const* d_in, const int* in_sizes, int n_in,
                              void* d_out, int out_size, void* d_ws, size_t ws_size,
                              hipStream_t stream) {
    const float* x   = (const float*)d_in[0];
    const int*   ei  = (const int*)d_in[1];
    const float* W1  = (const float*)d_in[2];
    const float* b1  = (const float*)d_in[3];
    const float* W2  = (const float*)d_in[4];
    const float* b2  = (const float*)d_in[5];
    const float* fcw = (const float*)d_in[6];
    const float* fcb = (const float*)d_in[7];
    float* out = (float*)d_out;

    char* ws = (char*)d_ws;
    float*          v      = (float*)(ws + OFF_V);
    unsigned int*   done   = (unsigned int*)(ws + OFF_DONE);
    int*            cnt    = (int*)(ws + OFF_CNT);
    float*          dinv   = (float*)(ws + OFF_DINV);
    float*          csum   = (float*)(ws + OFF_CSUM);
    unsigned short* ell    = (unsigned short*)(ws + OFF_ELL);
    __half*         xh     = (__half*)(ws + OFF_XH);
    __half*         xa     = (__half*)(ws + OFF_XA);
    unsigned short* cpart  = (unsigned short*)(ws + OFF_CPART);
    float*          cspart = (float*)(ws + OFF_CSP);

    hipMemsetAsync(ws, 0, ZBYTES, stream);

    k_count<<<FB, 1024, 0, stream>>>(ei, cpart);
    k_scan<<<10, 1024, 0, stream>>>(cpart, cnt, dinv);
    k_prep<<<FB + CB + HB, 1024, 0, stream>>>(ei, x, dinv, cpart, ell, cspart, xh);
    k_agg<<<AB + 40, 256, 0, stream>>>(x, xh, dinv, cnt, ell, cspart, csum, xa);
    k_gemmv<<<512, 256, 0, stream>>>(xa, W1, b1, dinv, csum, v, done,
                                     W2, b2, fcw, fcb, out);
}